// Round 16
// baseline (436.742 us; speedup 1.0000x reference)
//
#include <hip/hip_runtime.h>
#include <math.h>

#define N 8192
#define C 10
#define NUM_ITERS 5
#define FBLOCK 1024        /* 16 waves, 1 block/CU-ish, 4 waves/SIMD */
#define IBLK 32            /* i's per block */
#define NBLK (N / IBLK)    /* 256 blocks */
#define JW (N / 16)        /* 512 j's per wave */
#define NS (JW / 32)       /* 16 s-iters per wave, 32 j's each */
#define LOG2E 1.44269504088896340736f
#define C3 (LOG2E / 64.0f)

typedef _Float16 half8 __attribute__((ext_vector_type(8)));
typedef _Float16 half4 __attribute__((ext_vector_type(4)));
typedef _Float16 half2 __attribute__((ext_vector_type(2)));
typedef float f32x4 __attribute__((ext_vector_type(4)));
typedef float f32x16 __attribute__((ext_vector_type(16)));

// ws layout:
//   ajs half8[N] 128KB ; ajb half8[N] 128KB
//   pf0/pf1 f16[N/16][16][16] : probs, J-TILED
//   cnt u32[8] @2MB           : global-barrier counters (one slot per barrier)
#define WS_AJS 0
#define WS_AJB (N * 16)
#define WS_PF0 (N * 32)
#define WS_PF1 (N * 64)
#define WS_CNT (2 * 1024 * 1024)
#define PFIDX(n, c) ((((n) >> 4) * 16 + (c)) * 16 + ((n) & 15))

static __device__ __forceinline__ unsigned int pkexp(float a, float b) {
    float ea = __builtin_amdgcn_exp2f(a);
    float eb = __builtin_amdgcn_exp2f(b);
    return __builtin_bit_cast(unsigned int, __builtin_amdgcn_cvt_pkrtz(ea, eb));
}

static __device__ __forceinline__ half8 rdfrag(const unsigned int* R, int q) {
    uint2 lo = *(const uint2*)&R[2 * q];
    uint2 hi = *(const uint2*)&R[8 + 2 * q];
    half2 a = __builtin_bit_cast(half2, lo.x);
    half2 b = __builtin_bit_cast(half2, lo.y);
    half2 c = __builtin_bit_cast(half2, hi.x);
    half2 d = __builtin_bit_cast(half2, hi.y);
    half8 r = {a[0], a[1], b[0], b[1], c[0], c[1], d[0], d[1]};
    return r;
}

// once per launch: aug features + softmax(unaries) -> pf0 (tiled); zero rows
// 10..15 of both pf; zero barrier counters (re-zeroed every launch/replay).
__global__ __launch_bounds__(256) void init_kernel(
    const float* __restrict__ unaries, const float* __restrict__ feat,
    half8* __restrict__ ajs8, half8* __restrict__ ajb8,
    _Float16* __restrict__ pf0, _Float16* __restrict__ pf1,
    unsigned int* __restrict__ cnt) {
    int n = blockIdx.x * 256 + threadIdx.x;
    if (blockIdx.x == 0 && threadIdx.x < 8) cnt[threadIdx.x] = 0u;
    float f6[6];
#pragma unroll
    for (int d = 0; d < 6; ++d) f6[d] = feat[d * N + n];
    float h3 = 0.5f * (f6[0] * f6[0] + f6[1] * f6[1] + f6[2] * f6[2]);
    float h6v = h3 + 0.5f * (f6[3] * f6[3] + f6[4] * f6[4] + f6[5] * f6[5]);
    half8 a = {};
    a[0] = (_Float16)(f6[0] * C3);
    a[1] = (_Float16)(f6[1] * C3);
    a[2] = (_Float16)(f6[2] * C3);
    a[6] = (_Float16)(-h3 * C3);
    a[7] = (_Float16)1.0f;
    ajs8[n] = a;
    half8 b;
#pragma unroll
    for (int d = 0; d < 6; ++d) b[d] = (_Float16)(f6[d] * LOG2E);
    b[6] = (_Float16)(-h6v * LOG2E);
    b[7] = (_Float16)1.0f;
    ajb8[n] = b;

    float q[C];
#pragma unroll
    for (int c = 0; c < C; ++c) q[c] = unaries[c * N + n];
    float m = q[0];
#pragma unroll
    for (int c = 1; c < C; ++c) m = fmaxf(m, q[c]);
    float e[C], s = 0.0f;
#pragma unroll
    for (int c = 0; c < C; ++c) {
        e[c] = __builtin_amdgcn_exp2f((q[c] - m) * LOG2E);
        s += e[c];
    }
    float inv = 1.0f / s;
#pragma unroll
    for (int c = 0; c < C; ++c) pf0[PFIDX(n, c)] = (_Float16)(e[c] * inv);
#pragma unroll
    for (int c = C; c < 16; ++c) {
        pf0[PFIDX(n, c)] = (_Float16)0.0f;
        pf1[PFIDX(n, c)] = (_Float16)0.0f;
    }
}

union FusedLds {
    unsigned int wt[16][2][32][18];
    float rbuf[16 * 1024];
};

// one full CRF iteration: main loop + cross-wave reduce + combine/softmax.
static __device__ __forceinline__ void fused_body(
    FusedLds* sm, int t, int i0,
    const float* __restrict__ unaries, const float* __restrict__ SW,
    const float* __restrict__ BW, const float* __restrict__ CM,
    const char* __restrict__ ajs_c, const char* __restrict__ ajb_c,
    const _Float16* __restrict__ pf_in, _Float16* __restrict__ pf_out,
    float* __restrict__ out, int is_last, half8 b1s, half8 b1b) {
    int lane = t & 63;
    int w = t >> 6;
    int il = lane & 15;
    int quad = lane >> 4;
    int li = lane & 31;
    int hs = lane >> 5;
    const f32x4 zero4 = {0.f, 0.f, 0.f, 0.f};
    const f32x16 zero16 = {};

    f32x4 as0 = zero4, as1 = zero4, ab0 = zero4, ab1 = zero4;
    int jw = w * JW;
    const half4* pfv = (const half4*)pf_in;
    unsigned int* Ws = &sm->wt[w][0][li][0];
    unsigned int* Wb = &sm->wt[w][1][li][0];
    const unsigned int* R0s = &sm->wt[w][0][il][0];
    const unsigned int* R1s = &sm->wt[w][0][16 + il][0];
    const unsigned int* R0b = &sm->wt[w][1][il][0];
    const unsigned int* R1b = &sm->wt[w][1][16 + il][0];

    {
        int ph = w & 3;
        if (ph == 1) __builtin_amdgcn_s_sleep(2);
        else if (ph == 2) __builtin_amdgcn_s_sleep(4);
        else if (ph == 3) __builtin_amdgcn_s_sleep(6);
    }

    for (int k = 0; k < NS; ++k) {
        int j0 = jw + k * 32;
        half4 av_s = *(const half4*)(ajs_c + (size_t)(j0 + li) * 16 + hs * 8);
        half4 av_b = *(const half4*)(ajb_c + (size_t)(j0 + li) * 16 + hs * 8);
        half4 cp0 = pfv[((j0 >> 4) * 16 + il) * 4 + quad];
        half4 cp1 = pfv[(((j0 >> 4) + 1) * 16 + il) * 4 + quad];
        half8 A_s = {av_s[0], av_s[1], av_s[2], av_s[3], (_Float16)0.0f,
                     (_Float16)0.0f, (_Float16)0.0f, (_Float16)0.0f};
        half8 A_b = {av_b[0], av_b[1], av_b[2], av_b[3], (_Float16)0.0f,
                     (_Float16)0.0f, (_Float16)0.0f, (_Float16)0.0f};
        half8 Bp = {cp0[0], cp0[1], cp0[2], cp0[3], cp1[0], cp1[1], cp1[2], cp1[3]};

        __builtin_amdgcn_s_setprio(1);
        f32x16 d1s = __builtin_amdgcn_mfma_f32_32x32x16_f16(A_s, b1s, zero16, 0, 0, 0);
        f32x16 d1b = __builtin_amdgcn_mfma_f32_32x32x16_f16(A_b, b1b, zero16, 0, 0, 0);
        __builtin_amdgcn_s_setprio(0);

        {
            uint2 v;
            v.x = pkexp(d1s[0], d1s[1]);  v.y = pkexp(d1s[2], d1s[3]);
            *(uint2*)&Ws[0 + 2 * hs] = v;
            v.x = pkexp(d1s[4], d1s[5]);  v.y = pkexp(d1s[6], d1s[7]);
            *(uint2*)&Ws[4 + 2 * hs] = v;
            v.x = pkexp(d1s[8], d1s[9]);  v.y = pkexp(d1s[10], d1s[11]);
            *(uint2*)&Ws[8 + 2 * hs] = v;
            v.x = pkexp(d1s[12], d1s[13]); v.y = pkexp(d1s[14], d1s[15]);
            *(uint2*)&Ws[12 + 2 * hs] = v;
            v.x = pkexp(d1b[0], d1b[1]);  v.y = pkexp(d1b[2], d1b[3]);
            *(uint2*)&Wb[0 + 2 * hs] = v;
            v.x = pkexp(d1b[4], d1b[5]);  v.y = pkexp(d1b[6], d1b[7]);
            *(uint2*)&Wb[4 + 2 * hs] = v;
            v.x = pkexp(d1b[8], d1b[9]);  v.y = pkexp(d1b[10], d1b[11]);
            *(uint2*)&Wb[8 + 2 * hs] = v;
            v.x = pkexp(d1b[12], d1b[13]); v.y = pkexp(d1b[14], d1b[15]);
            *(uint2*)&Wb[12 + 2 * hs] = v;
        }
        half8 A00 = rdfrag(R0s, quad);
        half8 A01 = rdfrag(R1s, quad);
        half8 A10 = rdfrag(R0b, quad);
        half8 A11 = rdfrag(R1b, quad);
        __builtin_amdgcn_s_setprio(1);
        as0 = __builtin_amdgcn_mfma_f32_16x16x32_f16(A00, Bp, as0, 0, 0, 0);
        as1 = __builtin_amdgcn_mfma_f32_16x16x32_f16(A01, Bp, as1, 0, 0, 0);
        ab0 = __builtin_amdgcn_mfma_f32_16x16x32_f16(A10, Bp, ab0, 0, 0, 0);
        ab1 = __builtin_amdgcn_mfma_f32_16x16x32_f16(A11, Bp, ab1, 0, 0, 0);
        __builtin_amdgcn_s_setprio(0);
    }

    __syncthreads();
    {
        float* rb = sm->rbuf + w * 1024;
#pragma unroll
        for (int r = 0; r < 4; ++r) {
            rb[r * 64 + lane]       = as0[r];
            rb[256 + r * 64 + lane] = as1[r];
            rb[512 + r * 64 + lane] = ab0[r];
            rb[768 + r * 64 + lane] = ab1[r];
        }
    }
    __syncthreads();
    {
        float tot = 0.f;
#pragma unroll
        for (int w2 = 0; w2 < 16; ++w2) tot += sm->rbuf[w2 * 1024 + t];
        sm->rbuf[t] = tot;
    }
    __syncthreads();

    if (t < IBLK) {
        int i = i0 + t;
        int sub = t >> 4, ql = (t & 15) >> 2, rr = t & 3;
        float sp[C], bl[C];
#pragma unroll
        for (int c = 0; c < C; ++c) {
            int base = sub * 256 + rr * 64 + ql * 16 + c;
            sp[c] = sm->rbuf[base];
            bl[c] = sm->rbuf[base + 512];
        }
        float msg[C];
#pragma unroll
        for (int c = 0; c < C; ++c) {
            float m = 0.f;
#pragma unroll
            for (int kk = 0; kk < C; ++kk)
                m += SW[c * C + kk] * sp[kk] + BW[c * C + kk] * bl[kk];
            msg[c] = m;
        }
        float qq[C];
#pragma unroll
        for (int c = 0; c < C; ++c) {
            float pw = 0.f;
#pragma unroll
            for (int kk = 0; kk < C; ++kk) pw += CM[c * C + kk] * msg[kk];
            qq[c] = unaries[c * N + i] - pw;
        }
        if (is_last) {
#pragma unroll
            for (int c = 0; c < C; ++c) out[c * N + i] = qq[c];
        } else {
            float m = qq[0];
#pragma unroll
            for (int c = 1; c < C; ++c) m = fmaxf(m, qq[c]);
            float e[C], s = 0.0f;
#pragma unroll
            for (int c = 0; c < C; ++c) {
                e[c] = __builtin_amdgcn_exp2f((qq[c] - m) * LOG2E);
                s += e[c];
            }
            float inv = 1.0f / s;
#pragma unroll
            for (int c = 0; c < C; ++c) pf_out[PFIDX(i, c)] = (_Float16)(e[c] * inv);
        }
    }
}

static __device__ __forceinline__ void make_b1(
    const float* __restrict__ feat, int i0, int li, int hs,
    half8& b1s, half8& b1b) {
    int i = i0 + li;
    float g0 = feat[0 * N + i], g1 = feat[1 * N + i], g2 = feat[2 * N + i];
    float g3 = feat[3 * N + i], g4 = feat[4 * N + i], g5 = feat[5 * N + i];
    float h3 = 0.5f * (g0 * g0 + g1 * g1 + g2 * g2);
    float h6v = h3 + 0.5f * (g3 * g3 + g4 * g4 + g5 * g5);
    half4 slo = {(_Float16)g0, (_Float16)g1, (_Float16)g2, (_Float16)0.0f};
    half4 shi = {(_Float16)0.0f, (_Float16)0.0f, (_Float16)1.0f, (_Float16)(-h3 * C3)};
    half4 blo = {(_Float16)g0, (_Float16)g1, (_Float16)g2, (_Float16)g3};
    half4 bhi = {(_Float16)g4, (_Float16)g5, (_Float16)1.0f, (_Float16)(-h6v * LOG2E)};
    half4 sv = hs ? shi : slo;
    half4 bv = hs ? bhi : blo;
    half8 t1 = {sv[0], sv[1], sv[2], sv[3], (_Float16)0.0f, (_Float16)0.0f,
                (_Float16)0.0f, (_Float16)0.0f};
    half8 t2 = {bv[0], bv[1], bv[2], bv[3], (_Float16)0.0f, (_Float16)0.0f,
                (_Float16)0.0f, (_Float16)0.0f};
    b1s = t1;
    b1b = t2;
}

// ============ single-dispatch CRF: 5 iterations, hand-rolled global barrier ============
// 256 blocks x 1024 thr; LDS 73.7KB -> all blocks co-resident (even at 2/CU
// packing, 128 CUs suffice). Barrier = release-fence + counter-atomic + spin
// (device-scope loads bypass L1) + acquire-fence (L1 inv). One counter slot
// per barrier, zeroed by init each launch/replay. R7 precedent: flag-waiting
// at this grid size is deadlock-free.
__global__ __launch_bounds__(FBLOCK, 4) void crf_kernel(
    const float* __restrict__ unaries, const float* __restrict__ feat,
    const float* __restrict__ SW, const float* __restrict__ BW,
    const float* __restrict__ CM,
    const char* __restrict__ ajs_c, const char* __restrict__ ajb_c,
    _Float16* __restrict__ pf0, _Float16* __restrict__ pf1,
    float* __restrict__ out, unsigned int* __restrict__ cnt) {
    __shared__ FusedLds sm;
    int t = threadIdx.x;
    int i0 = blockIdx.x * IBLK;
    half8 b1s, b1b;
    make_b1(feat, i0, t & 31, (t & 63) >> 5, b1s, b1b);

    const _Float16* pin = pf0;
    _Float16* pout = pf1;
    for (int it = 0; it < NUM_ITERS; ++it) {
        fused_body(&sm, t, i0, unaries, SW, BW, CM, ajs_c, ajb_c, pin, pout, out,
                   it == NUM_ITERS - 1 ? 1 : 0, b1s, b1b);
        if (it < NUM_ITERS - 1) {
            // ---- global barrier #it ----
            __threadfence();        // release: flush this thread's pf stores to L2/device
            __syncthreads();        // all threads of block have fenced
            if (t == 0) {
                __hip_atomic_fetch_add(&cnt[it], 1u, __ATOMIC_RELEASE,
                                       __HIP_MEMORY_SCOPE_AGENT);
                while (__hip_atomic_load(&cnt[it], __ATOMIC_RELAXED,
                                         __HIP_MEMORY_SCOPE_AGENT) < (unsigned)NBLK)
                    __builtin_amdgcn_s_sleep(8);
                __builtin_amdgcn_fence(__ATOMIC_ACQUIRE, "agent");  // L1 invalidate
            }
            __syncthreads();        // whole block waits for t0's acquire
            const _Float16* tmp = pin;
            pin = pout;
            pout = (_Float16*)tmp;
        }
    }
}

extern "C" void kernel_launch(void* const* d_in, const int* in_sizes, int n_in,
                              void* d_out, int out_size, void* d_ws, size_t ws_size,
                              hipStream_t stream) {
    const float* unaries = (const float*)d_in[0];   // [10, 8192]
    const float* feat    = (const float*)d_in[1];   // [6, 8192]
    const float* SW      = (const float*)d_in[2];   // [10,10]
    const float* BW      = (const float*)d_in[3];   // [10,10]
    const float* CM      = (const float*)d_in[4];   // [10,10]
    float* out = (float*)d_out;

    char* ws = (char*)d_ws;
    half8* ajs    = (half8*)(ws + WS_AJS);
    half8* ajb    = (half8*)(ws + WS_AJB);
    _Float16* pf0 = (_Float16*)(ws + WS_PF0);
    _Float16* pf1 = (_Float16*)(ws + WS_PF1);
    unsigned int* cnt = (unsigned int*)(ws + WS_CNT);

    init_kernel<<<N / 256, 256, 0, stream>>>(unaries, feat, ajs, ajb, pf0, pf1, cnt);
    crf_kernel<<<NBLK, FBLOCK, 0, stream>>>(
        unaries, feat, SW, BW, CM, (const char*)ajs, (const char*)ajb,
        pf0, pf1, out, cnt);
}

// Round 17
// 161.814 us; speedup vs baseline: 2.6990x; 2.6990x over previous
//
#include <hip/hip_runtime.h>
#include <math.h>

#define N 8192
#define C 10
#define NUM_ITERS 5
#define FBLOCK 1024        /* 16 waves, 1 block/CU, 4 waves/SIMD */
#define IBLK 32            /* i's per block */
#define NBLK (N / IBLK)    /* 256 blocks = 1 per CU */
#define JW (N / 16)        /* 512 j's per wave */
#define NS (JW / 32)       /* 16 s-iters per wave, 32 j's each */
#define LOG2E 1.44269504088896340736f
#define C3 (LOG2E / 64.0f)

typedef _Float16 half8 __attribute__((ext_vector_type(8)));
typedef _Float16 half4 __attribute__((ext_vector_type(4)));
typedef _Float16 half2 __attribute__((ext_vector_type(2)));
typedef float f32x4 __attribute__((ext_vector_type(4)));
typedef float f32x16 __attribute__((ext_vector_type(16)));
typedef unsigned int uint4v __attribute__((ext_vector_type(4)));

// ws layout:
//   ajs half8[N] 128KB ; ajb half8[N] 128KB
//   pf0/pf1 f16[N/16][16][16] : probs, J-TILED (tile jt, row c, col j&15)
#define WS_AJS 0
#define WS_AJB (N * 16)
#define WS_PF0 (N * 32)
#define WS_PF1 (N * 64)
#define PFIDX(n, c) ((((n) >> 4) * 16 + (c)) * 16 + ((n) & 15))

static __device__ __forceinline__ unsigned int pkexp(float a, float b) {
    float ea = __builtin_amdgcn_exp2f(a);
    float eb = __builtin_amdgcn_exp2f(b);
    return __builtin_bit_cast(unsigned int, __builtin_amdgcn_cvt_pkrtz(ea, eb));
}

static __device__ __forceinline__ half8 mk8(unsigned int a, unsigned int b,
                                            unsigned int c, unsigned int d) {
    uint4v v = {a, b, c, d};
    return __builtin_bit_cast(half8, v);
}

// once per launch: aug features + softmax(unaries) -> pf0 (tiled); zero rows 10..15 both
__global__ __launch_bounds__(256) void init_kernel(
    const float* __restrict__ unaries, const float* __restrict__ feat,
    half8* __restrict__ ajs8, half8* __restrict__ ajb8,
    _Float16* __restrict__ pf0, _Float16* __restrict__ pf1) {
    int n = blockIdx.x * 256 + threadIdx.x;
    float f6[6];
#pragma unroll
    for (int d = 0; d < 6; ++d) f6[d] = feat[d * N + n];
    float h3 = 0.5f * (f6[0] * f6[0] + f6[1] * f6[1] + f6[2] * f6[2]);
    float h6v = h3 + 0.5f * (f6[3] * f6[3] + f6[4] * f6[4] + f6[5] * f6[5]);
    half8 a = {};
    a[0] = (_Float16)(f6[0] * C3);
    a[1] = (_Float16)(f6[1] * C3);
    a[2] = (_Float16)(f6[2] * C3);
    a[6] = (_Float16)(-h3 * C3);
    a[7] = (_Float16)1.0f;
    ajs8[n] = a;
    half8 b;
#pragma unroll
    for (int d = 0; d < 6; ++d) b[d] = (_Float16)(f6[d] * LOG2E);
    b[6] = (_Float16)(-h6v * LOG2E);
    b[7] = (_Float16)1.0f;
    ajb8[n] = b;

    float q[C];
#pragma unroll
    for (int c = 0; c < C; ++c) q[c] = unaries[c * N + n];
    float m = q[0];
#pragma unroll
    for (int c = 1; c < C; ++c) m = fmaxf(m, q[c]);
    float e[C], s = 0.0f;
#pragma unroll
    for (int c = 0; c < C; ++c) {
        e[c] = __builtin_amdgcn_exp2f((q[c] - m) * LOG2E);
        s += e[c];
    }
    float inv = 1.0f / s;
#pragma unroll
    for (int c = 0; c < C; ++c) pf0[PFIDX(n, c)] = (_Float16)(e[c] * inv);
#pragma unroll
    for (int c = C; c < 16; ++c) {
        pf0[PFIDX(n, c)] = (_Float16)0.0f;
        pf1[PFIDX(n, c)] = (_Float16)0.0f;
    }
}

// one dispatch per CRF iteration. Block owns 32 i's; wave sweeps its 512-j slice.
// Per s-iter (32 j's = 2 K-chunks of 16):
//   G1: D1[j][i] = 2x mfma_32x32x16 (one per filter), aug-K=16
//   exp+cvt_pk: D1 regs pair-packed -> w. KEY: D1's C/D layout == B-operand
//   layout of 32x32x16 (pass-decomposition symmetry), so w feeds GEMM-2
//   DIRECTLY from registers -- zero LDS in the main loop.
//   G2: D2[c][i] += p[c][j] * w[j][i] = 4x mfma_32x32x16 (A = p-frags, two
//   contiguous half4 loads per chunk from PFIDX; c-rows 16..31 are discarded).
__global__ __launch_bounds__(FBLOCK, 4) void fused_kernel(
    const float* __restrict__ unaries, const float* __restrict__ feat,
    const float* __restrict__ SW, const float* __restrict__ BW,
    const float* __restrict__ CM,
    const char* __restrict__ ajs_c, const char* __restrict__ ajb_c,
    const _Float16* __restrict__ pf_in, _Float16* __restrict__ pf_out,
    float* __restrict__ out, int is_last) {
    __shared__ float rbuf[16 * 640];   // 40 KB, epilogue only
    int t = threadIdx.x;
    int i0 = blockIdx.x * IBLK;
    int lane = t & 63;
    int w = t >> 6;
    int li = lane & 31;      // i (G1/G2 D col) or j (G1 A row) within 32
    int hs = lane >> 5;      // K-half select
    int cr = li & 15;        // clamped p-row for G2 A-operand (rows 16..31 garbage, discarded)
    const f32x16 zero16 = {};

    // ---- B1 fragments (G1 B-operand): lane holds aug[4hs..4hs+3] of i=i0+li ----
    half8 b1s, b1b;
    {
        int i = i0 + li;
        float g0 = feat[0 * N + i], g1 = feat[1 * N + i], g2 = feat[2 * N + i];
        float g3 = feat[3 * N + i], g4 = feat[4 * N + i], g5 = feat[5 * N + i];
        float h3 = 0.5f * (g0 * g0 + g1 * g1 + g2 * g2);
        float h6v = h3 + 0.5f * (g3 * g3 + g4 * g4 + g5 * g5);
        half4 slo = {(_Float16)g0, (_Float16)g1, (_Float16)g2, (_Float16)0.0f};
        half4 shi = {(_Float16)0.0f, (_Float16)0.0f, (_Float16)1.0f, (_Float16)(-h3 * C3)};
        half4 blo = {(_Float16)g0, (_Float16)g1, (_Float16)g2, (_Float16)g3};
        half4 bhi = {(_Float16)g4, (_Float16)g5, (_Float16)1.0f, (_Float16)(-h6v * LOG2E)};
        half4 sv = hs ? shi : slo;
        half4 bv = hs ? bhi : blo;
        half8 t1 = {sv[0], sv[1], sv[2], sv[3], (_Float16)0.0f, (_Float16)0.0f,
                    (_Float16)0.0f, (_Float16)0.0f};
        half8 t2 = {bv[0], bv[1], bv[2], bv[3], (_Float16)0.0f, (_Float16)0.0f,
                    (_Float16)0.0f, (_Float16)0.0f};
        b1s = t1;
        b1b = t2;
    }

    f32x16 acc_s = zero16, acc_b = zero16;
    int jw = w * JW;

    // convoy-breaking wave stagger (no sync points in main loop -> persists)
    {
        int ph = w & 3;
        if (ph == 1) __builtin_amdgcn_s_sleep(2);
        else if (ph == 2) __builtin_amdgcn_s_sleep(4);
        else if (ph == 3) __builtin_amdgcn_s_sleep(6);
    }

    for (int k = 0; k < NS; ++k) {
        int j0 = jw + k * 32;
        int jt0 = j0 >> 4;
        // G1 A-operand: aug[4hs..4hs+3] of j = j0+li
        half4 av_s = *(const half4*)(ajs_c + (size_t)(j0 + li) * 16 + hs * 8);
        half4 av_b = *(const half4*)(ajb_c + (size_t)(j0 + li) * 16 + hs * 8);
        // G2 A-operand (p-frags, shared by both filters): lane row c=li (clamped),
        // k-sets {4hs..4hs+3} and {8+4hs..11+4hs} within each 16-j chunk.
        const _Float16* pr0 = pf_in + (size_t)(jt0 * 16 + cr) * 16;
        const _Float16* pr1 = pf_in + (size_t)((jt0 + 1) * 16 + cr) * 16;
        half4 p0l = *(const half4*)&pr0[4 * hs];
        half4 p0h = *(const half4*)&pr0[8 + 4 * hs];
        half4 p1l = *(const half4*)&pr1[4 * hs];
        half4 p1h = *(const half4*)&pr1[8 + 4 * hs];
        half8 A20 = {p0l[0], p0l[1], p0l[2], p0l[3], p0h[0], p0h[1], p0h[2], p0h[3]};
        half8 A21 = {p1l[0], p1l[1], p1l[2], p1l[3], p1h[0], p1h[1], p1h[2], p1h[3]};
        half8 A_s = {av_s[0], av_s[1], av_s[2], av_s[3], (_Float16)0.0f,
                     (_Float16)0.0f, (_Float16)0.0f, (_Float16)0.0f};
        half8 A_b = {av_b[0], av_b[1], av_b[2], av_b[3], (_Float16)0.0f,
                     (_Float16)0.0f, (_Float16)0.0f, (_Float16)0.0f};

        // GEMM-1: D1[j][i] (col=li=i, row j=(r&3)+8(r>>2)+4hs), one per filter
        __builtin_amdgcn_s_setprio(1);
        f32x16 d1s = __builtin_amdgcn_mfma_f32_32x32x16_f16(A_s, b1s, zero16, 0, 0, 0);
        f32x16 d1b = __builtin_amdgcn_mfma_f32_32x32x16_f16(A_b, b1b, zero16, 0, 0, 0);
        __builtin_amdgcn_s_setprio(0);

        // exp + pack: D1 reg pairs ARE the B-frag u32s (layout match)
        half8 Bs0 = mk8(pkexp(d1s[0], d1s[1]), pkexp(d1s[2], d1s[3]),
                        pkexp(d1s[4], d1s[5]), pkexp(d1s[6], d1s[7]));
        half8 Bs1 = mk8(pkexp(d1s[8], d1s[9]), pkexp(d1s[10], d1s[11]),
                        pkexp(d1s[12], d1s[13]), pkexp(d1s[14], d1s[15]));
        half8 Bb0 = mk8(pkexp(d1b[0], d1b[1]), pkexp(d1b[2], d1b[3]),
                        pkexp(d1b[4], d1b[5]), pkexp(d1b[6], d1b[7]));
        half8 Bb1 = mk8(pkexp(d1b[8], d1b[9]), pkexp(d1b[10], d1b[11]),
                        pkexp(d1b[12], d1b[13]), pkexp(d1b[14], d1b[15]));

        // GEMM-2: D2[c][i] += p[c][j] w[j][i], straight from registers
        __builtin_amdgcn_s_setprio(1);
        acc_s = __builtin_amdgcn_mfma_f32_32x32x16_f16(A20, Bs0, acc_s, 0, 0, 0);
        acc_s = __builtin_amdgcn_mfma_f32_32x32x16_f16(A21, Bs1, acc_s, 0, 0, 0);
        acc_b = __builtin_amdgcn_mfma_f32_32x32x16_f16(A20, Bb0, acc_b, 0, 0, 0);
        acc_b = __builtin_amdgcn_mfma_f32_32x32x16_f16(A21, Bb1, acc_b, 0, 0, 0);
        __builtin_amdgcn_s_setprio(0);
    }

    // ---- dump valid acc rows to rbuf[w][filter][c][i] (c via row map) ----
    // acc row r -> c = (r&3) + 8*(r>>2) + 4*hs; valid c<10:
    //   hs=0: r0..3 -> c0..3, r4,r5 -> c8,c9 ; hs=1: r0..3 -> c4..7
    {
        float* rb = rbuf + w * 640;
        if (hs == 0) {
#pragma unroll
            for (int r = 0; r < 4; ++r) {
                rb[r * 32 + li]       = acc_s[r];
                rb[320 + r * 32 + li] = acc_b[r];
            }
            rb[8 * 32 + li] = acc_s[4];
            rb[9 * 32 + li] = acc_s[5];
            rb[320 + 8 * 32 + li] = acc_b[4];
            rb[320 + 9 * 32 + li] = acc_b[5];
        } else {
#pragma unroll
            for (int r = 0; r < 4; ++r) {
                rb[(4 + r) * 32 + li]       = acc_s[r];
                rb[320 + (4 + r) * 32 + li] = acc_b[r];
            }
        }
    }
    __syncthreads();
    if (t < 640) {
        float tot = 0.f;
#pragma unroll
        for (int w2 = 0; w2 < 16; ++w2) tot += rbuf[w2 * 640 + t];
        rbuf[t] = tot;   // slot t read only by thread t (w2=0 term)
    }
    __syncthreads();

    // ---- combine + compatibility + softmax for this block's 32 i's ----
    if (t < IBLK) {
        int i = i0 + t;
        float sp[C], bl[C];
#pragma unroll
        for (int c = 0; c < C; ++c) {
            sp[c] = rbuf[c * 32 + t];
            bl[c] = rbuf[320 + c * 32 + t];
        }
        float msg[C];
#pragma unroll
        for (int c = 0; c < C; ++c) {
            float m = 0.f;
#pragma unroll
            for (int kk = 0; kk < C; ++kk)
                m += SW[c * C + kk] * sp[kk] + BW[c * C + kk] * bl[kk];
            msg[c] = m;
        }
        float qq[C];
#pragma unroll
        for (int c = 0; c < C; ++c) {
            float pw = 0.f;
#pragma unroll
            for (int kk = 0; kk < C; ++kk) pw += CM[c * C + kk] * msg[kk];
            qq[c] = unaries[c * N + i] - pw;
        }
        if (is_last) {
#pragma unroll
            for (int c = 0; c < C; ++c) out[c * N + i] = qq[c];
        } else {
            float m = qq[0];
#pragma unroll
            for (int c = 1; c < C; ++c) m = fmaxf(m, qq[c]);
            float e[C], s = 0.0f;
#pragma unroll
            for (int c = 0; c < C; ++c) {
                e[c] = __builtin_amdgcn_exp2f((qq[c] - m) * LOG2E);
                s += e[c];
            }
            float inv = 1.0f / s;
#pragma unroll
            for (int c = 0; c < C; ++c) pf_out[PFIDX(i, c)] = (_Float16)(e[c] * inv);
        }
    }
}

extern "C" void kernel_launch(void* const* d_in, const int* in_sizes, int n_in,
                              void* d_out, int out_size, void* d_ws, size_t ws_size,
                              hipStream_t stream) {
    const float* unaries = (const float*)d_in[0];   // [10, 8192]
    const float* feat    = (const float*)d_in[1];   // [6, 8192]
    const float* SW      = (const float*)d_in[2];   // [10,10]
    const float* BW      = (const float*)d_in[3];   // [10,10]
    const float* CM      = (const float*)d_in[4];   // [10,10]
    float* out = (float*)d_out;

    char* ws = (char*)d_ws;
    half8* ajs    = (half8*)(ws + WS_AJS);
    half8* ajb    = (half8*)(ws + WS_AJB);
    _Float16* pf0 = (_Float16*)(ws + WS_PF0);
    _Float16* pf1 = (_Float16*)(ws + WS_PF1);

    init_kernel<<<N / 256, 256, 0, stream>>>(unaries, feat, ajs, ajb, pf0, pf1);
    const _Float16* pin = pf0;
    _Float16* pout = pf1;
    for (int it = 1; it <= NUM_ITERS; ++it) {
        fused_kernel<<<NBLK, FBLOCK, 0, stream>>>(
            unaries, feat, SW, BW, CM, (const char*)ajs, (const char*)ajb,
            pin, pout, out, it == NUM_ITERS ? 1 : 0);
        const _Float16* tmp = pout;
        pout = (_Float16*)pin;
        pin = tmp;
    }
}